// Round 2
// baseline (261.542 us; speedup 1.0000x reference)
//
#include <hip/hip_runtime.h>
#include <math.h>

#define NB 2
#define NL 256
#define DM 512
#define NH 8
#define DQ 64

// ---------------------------------------------------------------------------
// K1: QKV projection GEMM. C = X(512x512) @ W(512x512) + bias, output scattered
// into (b,h,l,d) fp32 layout. grid.z selects q/k/v.
// ---------------------------------------------------------------------------
__global__ __launch_bounds__(256) void qkv_gemm(
    const float* __restrict__ xq, const float* __restrict__ xk,
    const float* __restrict__ xv,
    const float* __restrict__ Wq, const float* __restrict__ Wk,
    const float* __restrict__ Wv,
    const float* __restrict__ bq, const float* __restrict__ bk,
    const float* __restrict__ bv,
    float* __restrict__ q, float* __restrict__ k, float* __restrict__ v)
{
    int z = blockIdx.z;
    const float* X = (z == 0) ? xq : (z == 1) ? xk : xv;
    const float* W = (z == 0) ? Wq : (z == 1) ? Wk : Wv;
    const float* bias = (z == 0) ? bq : (z == 1) ? bk : bv;
    float* O = (z == 0) ? q : (z == 1) ? k : v;

    __shared__ float As[16][65];   // [k][m]
    __shared__ float Bs[16][65];   // [k][n]

    int tid = threadIdx.x;
    int tx = tid & 15, ty = tid >> 4;
    int m0 = blockIdx.y * 64, n0 = blockIdx.x * 64;

    float acc[4][4] = {};

    for (int k0 = 0; k0 < 512; k0 += 16) {
        {   // A tile: 64 rows x 16 cols; thread: row tid>>2, 4 consecutive k
            int r = tid >> 2, c4 = (tid & 3) * 4;
            const float4 av = *(const float4*)(X + (m0 + r) * 512 + k0 + c4);
            As[c4 + 0][r] = av.x; As[c4 + 1][r] = av.y;
            As[c4 + 2][r] = av.z; As[c4 + 3][r] = av.w;
        }
        {   // B tile: 16 rows x 64 cols; thread: row tid>>4, 4 consecutive n
            int r = tid >> 4, c4 = (tid & 15) * 4;
            const float4 bv4 = *(const float4*)(W + (k0 + r) * 512 + n0 + c4);
            Bs[r][c4 + 0] = bv4.x; Bs[r][c4 + 1] = bv4.y;
            Bs[r][c4 + 2] = bv4.z; Bs[r][c4 + 3] = bv4.w;
        }
        __syncthreads();
        #pragma unroll
        for (int kk = 0; kk < 16; kk++) {
            float a[4], b[4];
            #pragma unroll
            for (int i = 0; i < 4; i++) a[i] = As[kk][ty * 4 + i];
            #pragma unroll
            for (int j = 0; j < 4; j++) b[j] = Bs[kk][tx * 4 + j];
            #pragma unroll
            for (int i = 0; i < 4; i++)
                #pragma unroll
                for (int j = 0; j < 4; j++) acc[i][j] += a[i] * b[j];
        }
        __syncthreads();
    }

    #pragma unroll
    for (int i = 0; i < 4; i++) {
        int m = m0 + ty * 4 + i;
        int b = m >> 8, l = m & 255;
        #pragma unroll
        for (int j = 0; j < 4; j++) {
            int n = n0 + tx * 4 + j;
            int h = n >> 6, d = n & 63;
            O[((b * NH + h) * NL + l) * DQ + d] = acc[i][j] + bias[n];
        }
    }
}

// ---------------------------------------------------------------------------
// K2: logits + softmax. One block per (b,h,q), thread = key position t.
// attn written directly to the f32 output buffer (output 1).
// ---------------------------------------------------------------------------
__global__ __launch_bounds__(256) void attn_kernel(
    const float* __restrict__ q, const float* __restrict__ k,
    const float* __restrict__ mask, float* __restrict__ attn_o)
{
    int qi = blockIdx.x, h = blockIdx.y, b = blockIdx.z;
    int t = threadIdx.x;

    __shared__ float qrow[64];
    __shared__ float red[256];

    const float* qp = q + ((b * NH + h) * NL + qi) * DQ;
    if (t < 64) qrow[t] = qp[t];
    __syncthreads();

    const float* kp = k + ((b * NH + h) * NL + t) * DQ;
    float acc = 0.f;
    #pragma unroll
    for (int d = 0; d < 64; d++) acc += qrow[d] * kp[d];
    acc *= 0.125f;   // 1/sqrt(64)

    float mv = mask[(b * NL + qi) * NL + t];
    acc -= (mv == 1.0f) ? INFINITY : mv;

    red[t] = acc; __syncthreads();
    for (int s = 128; s > 0; s >>= 1) { if (t < s) red[t] = fmaxf(red[t], red[t + s]); __syncthreads(); }
    float mx = red[0]; __syncthreads();

    float e = __expf(acc - mx);
    red[t] = e; __syncthreads();
    for (int s = 128; s > 0; s >>= 1) { if (t < s) red[t] += red[t + s]; __syncthreads(); }
    float sum = red[0];

    attn_o[((b * NH + h) * NL + qi) * NL + t] = e / sum;
}

// ---------------------------------------------------------------------------
// K3: u[b,h,t,e] = sum_d v[b,h,t,d] * (Win_re + i*Win_im)[h,d,e]
// ---------------------------------------------------------------------------
__global__ __launch_bounds__(256) void u_kernel(
    const float* __restrict__ v,
    const float* __restrict__ Wre, const float* __restrict__ Wim,
    float2* __restrict__ u)
{
    int e = threadIdx.x;            // 0..63
    int tq = threadIdx.y;           // 0..3
    int t = blockIdx.x * 4 + tq;
    int h = blockIdx.y, b = blockIdx.z;

    __shared__ float vrow[4][64];
    const float* vp = v + ((b * NH + h) * NL + t) * DQ;
    vrow[tq][e] = vp[e];
    __syncthreads();

    const float* wr = Wre + h * 4096 + e;
    const float* wi = Wim + h * 4096 + e;
    float ar = 0.f, ai = 0.f;
    #pragma unroll
    for (int d = 0; d < 64; d++) {
        float vv = vrow[tq][d];
        ar += vv * wr[d * 64];
        ai += vv * wi[d * 64];
    }
    u[((b * NH + h) * NL + t) * DQ + e] = make_float2(ar, ai);
}

// ---------------------------------------------------------------------------
// K4: the EUNN recurrence. One wave per (b,h,q); lane = complex state elem d.
//   h <- modrelu( U2(U1(h)) + a_t * u_t , bias )
// Layer0 pairs (2j,2j+1): partner = lane^1.
// Layer1 (rolled): odd lane role-a (partner d+1, j=d>>1), even lane role-b
//   (partner (d-1)&63, j=(d>>1 + 31)&31).
// Rotation collapses per lane: new = c*h + (w_re + i*w_im)*partner,
//   role-a: w = -sin*e^{i phi}, role-b: w = +sin*e^{-i phi}
//   => w_im = -sin*sin(phi) in both roles.
// ---------------------------------------------------------------------------
__global__ __launch_bounds__(256) void rnn_kernel(
    const float* __restrict__ attn_f, const float2* __restrict__ u,
    const float* __restrict__ theta, const float* __restrict__ phi,
    const float* __restrict__ rnn_bias,
    float* __restrict__ rnn_out)
{
    int wv = threadIdx.x >> 6;
    int lane = threadIdx.x & 63;
    int w = blockIdx.x * 4 + wv;          // 0..4095
    int qi = w & 255, h = (w >> 8) & 7, b = w >> 11;
    int d = lane;
    bool evenl = (d & 1) == 0;

    // layer 0 constants: theta[h,0,j0], phi[h,0,j0], j0 = d>>1
    int j0 = d >> 1;
    float th0 = theta[h * 64 + j0];
    float pp0 = phi[h * 64 + j0];
    float c0 = cosf(th0), s0 = sinf(th0);
    float w0r = (evenl ? -s0 : s0) * cosf(pp0);
    float w0i = -s0 * sinf(pp0);

    // layer 1 constants: theta[h,1,j1]
    int j1 = evenl ? ((j0 + 31) & 31) : j0;
    float th1 = theta[h * 64 + 32 + j1];
    float pp1 = phi[h * 64 + 32 + j1];
    float c1 = cosf(th1), s1 = sinf(th1);
    float w1r = (evenl ? s1 : -s1) * cosf(pp1);
    float w1i = -s1 * sinf(pp1);
    int p1 = evenl ? ((d + 63) & 63) : ((d + 1) & 63);

    float bias_d = rnn_bias[h * 64 + d];

    __shared__ float arow[4][256];
    const float* ap = attn_f + (size_t)w * 256;
    #pragma unroll
    for (int i = 0; i < 4; i++) arow[wv][lane + i * 64] = ap[lane + i * 64];
    __syncthreads();

    const float2* up = u + ((size_t)(b * NH + h) * NL) * DQ + d;

    float hr = 0.f, hi = 0.f;
    for (int t = 0; t < 256; t++) {
        // layer 0
        float pr = __shfl_xor(hr, 1, 64);
        float pi = __shfl_xor(hi, 1, 64);
        float t0r = c0 * hr + w0r * pr - w0i * pi;
        float t0i = c0 * hi + w0r * pi + w0i * pr;
        // layer 1
        pr = __shfl(t0r, p1, 64);
        pi = __shfl(t0i, p1, 64);
        float t1r = c1 * t0r + w1r * pr - w1i * pi;
        float t1i = c1 * t0i + w1r * pi + w1i * pr;
        // + a_t * u_t
        float2 uu = up[t * 64];
        float a_t = arow[wv][t];
        float zr = t1r + a_t * uu.x;
        float zi = t1i + a_t * uu.y;
        // modrelu
        float m = __builtin_amdgcn_sqrtf(zr * zr + zi * zi);
        float sc = fmaxf(m + bias_d, 0.f) * __builtin_amdgcn_rcpf(m + 1e-5f);
        hr = zr * sc;
        hi = zi * sc;
    }

    // real part, scattered into (B, L, DM) row-major for the output GEMM
    rnn_out[(b * NL + qi) * DM + h * DQ + d] = hr;
}

// ---------------------------------------------------------------------------
// K5: output projection. C = A(f32, 512x512) @ Wo + bo
// ---------------------------------------------------------------------------
__global__ __launch_bounds__(256) void out_gemm(
    const float* __restrict__ A, const float* __restrict__ W,
    const float* __restrict__ bias, float* __restrict__ C)
{
    __shared__ float As[16][65];
    __shared__ float Bs[16][65];

    int tid = threadIdx.x;
    int tx = tid & 15, ty = tid >> 4;
    int m0 = blockIdx.y * 64, n0 = blockIdx.x * 64;

    float acc[4][4] = {};

    for (int k0 = 0; k0 < 512; k0 += 16) {
        {
            int r = tid >> 2, c4 = (tid & 3) * 4;
            const float4 av = *(const float4*)(A + (m0 + r) * 512 + k0 + c4);
            As[c4 + 0][r] = av.x; As[c4 + 1][r] = av.y;
            As[c4 + 2][r] = av.z; As[c4 + 3][r] = av.w;
        }
        {
            int r = tid >> 4, c4 = (tid & 15) * 4;
            const float4 bv4 = *(const float4*)(W + (k0 + r) * 512 + n0 + c4);
            Bs[r][c4 + 0] = bv4.x; Bs[r][c4 + 1] = bv4.y;
            Bs[r][c4 + 2] = bv4.z; Bs[r][c4 + 3] = bv4.w;
        }
        __syncthreads();
        #pragma unroll
        for (int kk = 0; kk < 16; kk++) {
            float a[4], b[4];
            #pragma unroll
            for (int i = 0; i < 4; i++) a[i] = As[kk][ty * 4 + i];
            #pragma unroll
            for (int j = 0; j < 4; j++) b[j] = Bs[kk][tx * 4 + j];
            #pragma unroll
            for (int i = 0; i < 4; i++)
                #pragma unroll
                for (int j = 0; j < 4; j++) acc[i][j] += a[i] * b[j];
        }
        __syncthreads();
    }

    #pragma unroll
    for (int i = 0; i < 4; i++) {
        int m = m0 + ty * 4 + i;
        #pragma unroll
        for (int j = 0; j < 4; j++) {
            int n = n0 + tx * 4 + j;
            C[m * 512 + n] = acc[i][j] + bias[n];
        }
    }
}

// ---------------------------------------------------------------------------
extern "C" void kernel_launch(void* const* d_in, const int* in_sizes, int n_in,
                              void* d_out, int out_size, void* d_ws, size_t ws_size,
                              hipStream_t stream)
{
    const float* x_q  = (const float*)d_in[0];
    const float* x_k  = (const float*)d_in[1];
    const float* x_v  = (const float*)d_in[2];
    const float* mask = (const float*)d_in[3];
    const float* Wq   = (const float*)d_in[4];
    const float* bq   = (const float*)d_in[5];
    const float* Wk   = (const float*)d_in[6];
    const float* bk   = (const float*)d_in[7];
    const float* Wv   = (const float*)d_in[8];
    const float* bv   = (const float*)d_in[9];
    const float* Wo   = (const float*)d_in[10];
    const float* bo   = (const float*)d_in[11];
    const float* theta= (const float*)d_in[12];
    const float* phi  = (const float*)d_in[13];
    const float* Wre  = (const float*)d_in[14];
    const float* Wim  = (const float*)d_in[15];
    const float* rb   = (const float*)d_in[16];

    float* ws = (float*)d_ws;
    float*  q_ws    = ws;                       // 262144 f
    float*  k_ws    = ws + 262144;              // 262144 f
    float*  v_ws    = ws + 524288;              // 262144 f
    float2* u_ws    = (float2*)(ws + 786432);   // 262144 float2 = 524288 f
    float*  rnn_o   = ws + 1310720;             // 262144 f   (total 6 MiB)

    float* out_o  = (float*)d_out;              // (2,256,512)
    float* attn_o = out_o + NB * NL * DM;       // (2,8,256,256) at +262144

    qkv_gemm<<<dim3(8, 8, 3), 256, 0, stream>>>(
        x_q, x_k, x_v, Wq, Wk, Wv, bq, bk, bv, q_ws, k_ws, v_ws);

    attn_kernel<<<dim3(NL, NH, NB), 256, 0, stream>>>(
        q_ws, k_ws, mask, attn_o);

    u_kernel<<<dim3(NL / 4, NH, NB), dim3(64, 4), 0, stream>>>(
        v_ws, Wre, Wim, u_ws);

    rnn_kernel<<<dim3(1024), 256, 0, stream>>>(
        attn_o, u_ws, theta, phi, rb, rnn_o);

    out_gemm<<<dim3(8, 8), 256, 0, stream>>>(rnn_o, Wo, bo, out_o);
}

// Round 3
// 234.922 us; speedup vs baseline: 1.1133x; 1.1133x over previous
//
#include <hip/hip_runtime.h>
#include <math.h>

#define NB 2
#define NL 256
#define DM 512
#define NH 8
#define DQ 64

// ---------------------------------------------------------------------------
// K1: QKV projection GEMM. 32x64 tile, K-tile 32, thread tile 2x4.
// grid (8 n-tiles, 16 m-tiles, 3 gemms) = 384 blocks.
// ---------------------------------------------------------------------------
__global__ __launch_bounds__(256) void qkv_gemm(
    const float* __restrict__ xq, const float* __restrict__ xk,
    const float* __restrict__ xv,
    const float* __restrict__ Wq, const float* __restrict__ Wk,
    const float* __restrict__ Wv,
    const float* __restrict__ bq, const float* __restrict__ bk,
    const float* __restrict__ bv,
    float* __restrict__ q, float* __restrict__ k, float* __restrict__ v)
{
    int z = blockIdx.z;
    const float* X = (z == 0) ? xq : (z == 1) ? xk : xv;
    const float* W = (z == 0) ? Wq : (z == 1) ? Wk : Wv;
    const float* bias = (z == 0) ? bq : (z == 1) ? bk : bv;
    float* O = (z == 0) ? q : (z == 1) ? k : v;

    __shared__ float As[32][33];   // [k][m]
    __shared__ float Bs[32][68];   // [k][n], row stride 68 floats = 16B multiple

    int tid = threadIdx.x;
    int tx = tid & 15, ty = tid >> 4;      // tx: n-group, ty: m-pair
    int m0 = blockIdx.y * 32, n0 = blockIdx.x * 64;

    float acc[2][4] = {};

    for (int k0 = 0; k0 < 512; k0 += 32) {
        {   // A tile 32 rows x 32 k: thread r=tid>>3, c4=(tid&7)*4
            int r = tid >> 3, c4 = (tid & 7) * 4;
            const float4 av = *(const float4*)(X + (m0 + r) * 512 + k0 + c4);
            As[c4 + 0][r] = av.x; As[c4 + 1][r] = av.y;
            As[c4 + 2][r] = av.z; As[c4 + 3][r] = av.w;
        }
        {   // B tile 32 k x 64 n: thread rows (tid>>4) and (tid>>4)+16
            int r = tid >> 4, c4 = (tid & 15) * 4;
            float4 b0 = *(const float4*)(W + (k0 + r) * 512 + n0 + c4);
            float4 b1 = *(const float4*)(W + (k0 + r + 16) * 512 + n0 + c4);
            *(float4*)&Bs[r][c4] = b0;
            *(float4*)&Bs[r + 16][c4] = b1;
        }
        __syncthreads();
        #pragma unroll
        for (int kk = 0; kk < 32; kk++) {
            float a0 = As[kk][ty * 2 + 0];
            float a1 = As[kk][ty * 2 + 1];
            float4 bb = *(const float4*)&Bs[kk][tx * 4];
            acc[0][0] += a0 * bb.x; acc[0][1] += a0 * bb.y;
            acc[0][2] += a0 * bb.z; acc[0][3] += a0 * bb.w;
            acc[1][0] += a1 * bb.x; acc[1][1] += a1 * bb.y;
            acc[1][2] += a1 * bb.z; acc[1][3] += a1 * bb.w;
        }
        __syncthreads();
    }

    #pragma unroll
    for (int i = 0; i < 2; i++) {
        int m = m0 + ty * 2 + i;
        int b = m >> 8, l = m & 255;
        #pragma unroll
        for (int j = 0; j < 4; j++) {
            int n = n0 + tx * 4 + j;
            int h = n >> 6, d = n & 63;
            O[((b * NH + h) * NL + l) * DQ + d] = acc[i][j] + bias[n];
        }
    }
}

// ---------------------------------------------------------------------------
// K2: logits + softmax. One block per (b,h,q), lane = key t.
// Wave shfl reductions; 3 barriers total.
// ---------------------------------------------------------------------------
__global__ __launch_bounds__(256) void attn_kernel(
    const float* __restrict__ q, const float* __restrict__ k,
    const float* __restrict__ mask, float* __restrict__ attn_o)
{
    int qi = blockIdx.x, h = blockIdx.y, b = blockIdx.z;
    int tid = threadIdx.x;
    int wv = tid >> 6, lane = tid & 63;

    __shared__ float qrow[64];
    __shared__ float wred[4];
    __shared__ float wsum[4];

    if (tid < 16)
        ((float4*)qrow)[tid] = ((const float4*)(q + ((b * NH + h) * NL + qi) * DQ))[tid];
    __syncthreads();

    const float4* kp = (const float4*)(k + ((b * NH + h) * NL + tid) * DQ);
    float acc = 0.f;
    #pragma unroll
    for (int d4 = 0; d4 < 16; d4++) {
        float4 kv = kp[d4];
        float4 qv = ((const float4*)qrow)[d4];
        acc += qv.x * kv.x + qv.y * kv.y + qv.z * kv.z + qv.w * kv.w;
    }
    acc *= 0.125f;   // 1/sqrt(64)

    float mv = mask[(b * NL + qi) * NL + tid];
    acc -= (mv == 1.0f) ? INFINITY : mv;

    float mx = acc;
    #pragma unroll
    for (int o = 32; o; o >>= 1) mx = fmaxf(mx, __shfl_xor(mx, o, 64));
    if (lane == 0) wred[wv] = mx;
    __syncthreads();
    mx = fmaxf(fmaxf(wred[0], wred[1]), fmaxf(wred[2], wred[3]));

    float e = __expf(acc - mx);
    float s = e;
    #pragma unroll
    for (int o = 32; o; o >>= 1) s += __shfl_xor(s, o, 64);
    if (lane == 0) wsum[wv] = s;
    __syncthreads();
    s = wsum[0] + wsum[1] + wsum[2] + wsum[3];

    attn_o[((b * NH + h) * NL + qi) * NL + tid] = e * __builtin_amdgcn_rcpf(s);
}

// ---------------------------------------------------------------------------
// K3: u[b,h,t,e] = sum_d v[b,h,t,d] * (Win_re + i*Win_im)[h,d,e]
// ---------------------------------------------------------------------------
__global__ __launch_bounds__(256) void u_kernel(
    const float* __restrict__ v,
    const float* __restrict__ Wre, const float* __restrict__ Wim,
    float2* __restrict__ u)
{
    int e = threadIdx.x;            // 0..63
    int tq = threadIdx.y;           // 0..3
    int t = blockIdx.x * 4 + tq;
    int h = blockIdx.y, b = blockIdx.z;

    __shared__ float vrow[4][64];
    const float* vp = v + ((b * NH + h) * NL + t) * DQ;
    vrow[tq][e] = vp[e];
    __syncthreads();

    const float* wr = Wre + h * 4096 + e;
    const float* wi = Wim + h * 4096 + e;
    float ar = 0.f, ai = 0.f;
    #pragma unroll
    for (int d = 0; d < 64; d++) {
        float vv = vrow[tq][d];
        ar += vv * wr[d * 64];
        ai += vv * wi[d * 64];
    }
    u[((b * NH + h) * NL + t) * DQ + e] = make_float2(ar, ai);
}

// ---------------------------------------------------------------------------
// K4: EUNN recurrence. One wave per (b,h,q); lane = complex state elem d.
// u/a prefetched with distance 4 (addresses are t-indexed, independent of the
// recurrence) so L2/LDS latency is off the serial critical path.
// ---------------------------------------------------------------------------
__global__ __launch_bounds__(256) void rnn_kernel(
    const float* __restrict__ attn_f, const float2* __restrict__ u,
    const float* __restrict__ theta, const float* __restrict__ phi,
    const float* __restrict__ rnn_bias,
    float* __restrict__ rnn_out)
{
    int wv = threadIdx.x >> 6;
    int lane = threadIdx.x & 63;
    int w = blockIdx.x * 4 + wv;          // 0..4095
    int qi = w & 255, h = (w >> 8) & 7, b = w >> 11;
    int d = lane;
    bool evenl = (d & 1) == 0;

    int j0 = d >> 1;
    float th0 = theta[h * 64 + j0];
    float pp0 = phi[h * 64 + j0];
    float c0 = cosf(th0), s0 = sinf(th0);
    float w0r = (evenl ? -s0 : s0) * cosf(pp0);
    float w0i = -s0 * sinf(pp0);

    int j1 = evenl ? ((j0 + 31) & 31) : j0;
    float th1 = theta[h * 64 + 32 + j1];
    float pp1 = phi[h * 64 + 32 + j1];
    float c1 = cosf(th1), s1 = sinf(th1);
    float w1r = (evenl ? s1 : -s1) * cosf(pp1);
    float w1i = -s1 * sinf(pp1);
    int p1 = evenl ? ((d + 63) & 63) : ((d + 1) & 63);

    float bias_d = rnn_bias[h * 64 + d];

    __shared__ float arow[4][256];
    const float* ap = attn_f + (size_t)w * 256;
    #pragma unroll
    for (int i = 0; i < 4; i++) arow[wv][lane + i * 64] = ap[lane + i * 64];
    __syncthreads();

    const float2* up = u + ((size_t)(b * NH + h) * NL) * DQ + d;

    // prefetch pipeline, distance 4
    float2 ubuf[4];
    float abuf[4];
    #pragma unroll
    for (int i = 0; i < 4; i++) { ubuf[i] = up[i * 64]; abuf[i] = arow[wv][i]; }

    float hr = 0.f, hi = 0.f;
    #pragma unroll 4
    for (int t = 0; t < 256; t++) {
        float2 uu = ubuf[t & 3];
        float a_t = abuf[t & 3];
        int tn = (t + 4 < 256) ? t + 4 : 255;
        ubuf[t & 3] = up[tn * 64];
        abuf[t & 3] = arow[wv][tn];

        // layer 0
        float pr = __shfl_xor(hr, 1, 64);
        float pi = __shfl_xor(hi, 1, 64);
        float t0r = c0 * hr + w0r * pr - w0i * pi;
        float t0i = c0 * hi + w0r * pi + w0i * pr;
        // layer 1
        pr = __shfl(t0r, p1, 64);
        pi = __shfl(t0i, p1, 64);
        float t1r = c1 * t0r + w1r * pr - w1i * pi;
        float t1i = c1 * t0i + w1r * pi + w1i * pr;
        // + a_t * u_t
        float zr = t1r + a_t * uu.x;
        float zi = t1i + a_t * uu.y;
        // modrelu
        float m = __builtin_amdgcn_sqrtf(zr * zr + zi * zi);
        float sc = fmaxf(m + bias_d, 0.f) * __builtin_amdgcn_rcpf(m + 1e-5f);
        hr = zr * sc;
        hi = zi * sc;
    }

    rnn_out[(b * NL + qi) * DM + h * DQ + d] = hr;
}

// ---------------------------------------------------------------------------
// K5: output projection. 16x64 tile, K-tile 32, thread tile 1x4.
// grid (8 n-tiles, 32 m-tiles) = 256 blocks.
// ---------------------------------------------------------------------------
__global__ __launch_bounds__(256) void out_gemm(
    const float* __restrict__ A, const float* __restrict__ W,
    const float* __restrict__ bias, float* __restrict__ C)
{
    __shared__ float As[32][17];   // [k][m]
    __shared__ float Bs[32][68];   // [k][n]

    int tid = threadIdx.x;
    int tx = tid & 15, ty = tid >> 4;
    int m0 = blockIdx.y * 16, n0 = blockIdx.x * 64;

    float acc[4] = {};

    for (int k0 = 0; k0 < 512; k0 += 32) {
        {   // A tile 16 rows x 32 k: thread r=tid>>4, c2=(tid&15)*2
            int r = tid >> 4, c2 = (tid & 15) * 2;
            const float2 av = *(const float2*)(A + (m0 + r) * 512 + k0 + c2);
            As[c2 + 0][r] = av.x; As[c2 + 1][r] = av.y;
        }
        {   // B tile 32 k x 64 n
            int r = tid >> 4, c4 = (tid & 15) * 4;
            float4 b0 = *(const float4*)(W + (k0 + r) * 512 + n0 + c4);
            float4 b1 = *(const float4*)(W + (k0 + r + 16) * 512 + n0 + c4);
            *(float4*)&Bs[r][c4] = b0;
            *(float4*)&Bs[r + 16][c4] = b1;
        }
        __syncthreads();
        #pragma unroll
        for (int kk = 0; kk < 32; kk++) {
            float a = As[kk][ty];
            float4 bb = *(const float4*)&Bs[kk][tx * 4];
            acc[0] += a * bb.x; acc[1] += a * bb.y;
            acc[2] += a * bb.z; acc[3] += a * bb.w;
        }
        __syncthreads();
    }

    int m = m0 + ty;
    #pragma unroll
    for (int j = 0; j < 4; j++) {
        int n = n0 + tx * 4 + j;
        C[m * 512 + n] = acc[j] + bias[n];
    }
}

// ---------------------------------------------------------------------------
extern "C" void kernel_launch(void* const* d_in, const int* in_sizes, int n_in,
                              void* d_out, int out_size, void* d_ws, size_t ws_size,
                              hipStream_t stream)
{
    const float* x_q  = (const float*)d_in[0];
    const float* x_k  = (const float*)d_in[1];
    const float* x_v  = (const float*)d_in[2];
    const float* mask = (const float*)d_in[3];
    const float* Wq   = (const float*)d_in[4];
    const float* bq   = (const float*)d_in[5];
    const float* Wk   = (const float*)d_in[6];
    const float* bk   = (const float*)d_in[7];
    const float* Wv   = (const float*)d_in[8];
    const float* bv   = (const float*)d_in[9];
    const float* Wo   = (const float*)d_in[10];
    const float* bo   = (const float*)d_in[11];
    const float* theta= (const float*)d_in[12];
    const float* phi  = (const float*)d_in[13];
    const float* Wre  = (const float*)d_in[14];
    const float* Wim  = (const float*)d_in[15];
    const float* rb   = (const float*)d_in[16];

    float* ws = (float*)d_ws;
    float*  q_ws    = ws;                       // 262144 f
    float*  k_ws    = ws + 262144;              // 262144 f
    float*  v_ws    = ws + 524288;              // 262144 f
    float2* u_ws    = (float2*)(ws + 786432);   // 262144 float2
    float*  rnn_o   = ws + 1310720;             // 262144 f

    float* out_o  = (float*)d_out;              // (2,256,512)
    float* attn_o = out_o + NB * NL * DM;       // (2,8,256,256)

    qkv_gemm<<<dim3(8, 16, 3), 256, 0, stream>>>(
        x_q, x_k, x_v, Wq, Wk, Wv, bq, bk, bv, q_ws, k_ws, v_ws);

    attn_kernel<<<dim3(NL, NH, NB), 256, 0, stream>>>(
        q_ws, k_ws, mask, attn_o);

    u_kernel<<<dim3(NL / 4, NH, NB), dim3(64, 4), 0, stream>>>(
        v_ws, Wre, Wim, u_ws);

    rnn_kernel<<<dim3(1024), 256, 0, stream>>>(
        attn_o, u_ws, theta, phi, rb, rnn_o);

    out_gemm<<<dim3(8, 32), 256, 0, stream>>>(rnn_o, Wo, bo, out_o);
}